// Round 2
// baseline (994.440 us; speedup 1.0000x reference)
//
#include <hip/hip_runtime.h>
#include <stdint.h>

#define B_   16
#define T_   2048
#define C_   200
#define D_   2048
#define K_   (B_*T_)        // 32768
#define MT   13             // 16-row m-tiles (CP=208)
#define CP   (MT*16)
#define BN   64             // d-cols per WG
#define BK   32             // k per step
#define KSPLIT 32
#define KCHUNK (K_/KSPLIT)  // 1024
#define NSTEPS (KCHUNK/BK)  // 32
#define NKBLK  (K_/BK)      // 1024
#define BSTR 68             // Bs row stride in bf16 elems (136B: 8B-aligned writes, spread banks)

typedef short bf16x8 __attribute__((ext_vector_type(8)));
typedef float f32x4  __attribute__((ext_vector_type(4)));

__device__ __forceinline__ unsigned short f2bf(float f) {
    uint32_t u = __float_as_uint(f);
    u += 0x7FFFu + ((u >> 16) & 1u);
    return (unsigned short)(u >> 16);
}

__device__ __forceinline__ void gload_lds16(const void* g, void* l) {
    __builtin_amdgcn_global_load_lds(
        (const __attribute__((address_space(1))) unsigned int*)g,
        (__attribute__((address_space(3))) unsigned int*)l, 16, 0, 0);
}

// ---------------------------------------------------------------------------
// Kernel 1: build maskT in MFMA-fragment order, LDS-free, + counts.
// Fragment storage: frag(kblk, m) is 64 lanes x 16B; lane lf=(c&15)+lg*16
// holds bf16 mask[c][kblk*32+lg*8 .. +8]. Wave w of WG kb handles k-run
// kb*32 + w*8 (lg=w); lane l<52 owns c=4l..4l+3 -> four coalesced 16B writes.
// ---------------------------------------------------------------------------
__global__ __launch_bounds__(256) void mask_frag_kernel(
    const int* __restrict__ act, const int* __restrict__ vid,
    unsigned short* __restrict__ mfrag, int* __restrict__ counts) {
    __shared__ int cnt[CP];
    const int t = threadIdx.x, w = t >> 6, l = t & 63;
    const int kblk = blockIdx.x;
    const int k0 = kblk * 32 + w * 8;
    const int b  = k0 / T_;              // 8 | 2048: run never straddles b
    for (int i = t; i < CP; i += 256) cnt[i] = 0;
    __syncthreads();

    if (l < 52) {
        const int c0 = 4 * l;
        unsigned int vm[4] = {0u, 0u, 0u, 0u};
        int4 a[8];
        #pragma unroll
        for (int i = 0; i < 8; ++i) a[i] = make_int4(0, 0, 0, 0);
        if (l < 50) {
            int4 vd = *(const int4*)&vid[b * C_ + c0];
            vm[0] = vd.x ? 0x3F80u : 0u;  vm[1] = vd.y ? 0x3F80u : 0u;
            vm[2] = vd.z ? 0x3F80u : 0u;  vm[3] = vd.w ? 0x3F80u : 0u;
            #pragma unroll
            for (int i = 0; i < 8; ++i)
                a[i] = *(const int4*)&act[(size_t)(k0 + i) * C_ + c0];
        }
        const int m = c0 >> 4;
        // ushort index of this lane's first frag row
        size_t fb = ((size_t)(kblk * MT + m) * 64 + (c0 & 15) + w * 16) * 8;
        #pragma unroll
        for (int cc = 0; cc < 4; ++cc) {
            unsigned int u[8]; int s = 0;
            #pragma unroll
            for (int i = 0; i < 8; ++i) {
                int av = (&a[i].x)[cc];
                unsigned int v = av ? vm[cc] : 0u;
                u[i] = v; s += (v != 0u);
            }
            uint4 o = make_uint4(u[0] | (u[1] << 16), u[2] | (u[3] << 16),
                                 u[4] | (u[5] << 16), u[6] | (u[7] << 16));
            *(uint4*)&mfrag[fb + (size_t)cc * 8] = o;
            if (s) atomicAdd(&cnt[c0 + cc], s);
        }
    }
    __syncthreads();
    if (t < C_ && cnt[t]) atomicAdd(&counts[t], cnt[t]);
}

// ---------------------------------------------------------------------------
// Kernel 2: sums += mask @ feats.  A via global_load_lds (linear frag order,
// conflict-free b128 reads).  B staged bf16 [k][d] (8B linear writes); the
// k-contiguous fragment is assembled with lane-pair b32 reads + shfl_xor(1)
// + v_perm.  Waves: (mh,dh) = m-half x d-half.  Double-buffered, 1 barrier
// per step.  mode=1: plain-store partials[ks]; mode=0: atomicAdd into sums.
// ---------------------------------------------------------------------------
__global__ __launch_bounds__(256, 4) void gemm_kernel(
    const float* __restrict__ feats, const unsigned short* __restrict__ mfrag,
    float* __restrict__ outbuf, int mode) {
    __shared__ unsigned short Asd[2][MT * 512];   // 2 x 13312 B
    __shared__ unsigned short Bsd[2][BK * BSTR];  // 2 x 4352 B

    int bid = blockIdx.x;
    bid = (bid & 7) * 128 + (bid >> 3);           // XCD swizzle (1024 % 8 == 0)
    const int dt = bid & 31, ks = bid >> 5;
    const int d0 = dt * BN;
    const int kb0 = ks * NSTEPS;
    const int t = threadIdx.x, w = t >> 6, lane = t & 63;
    const int l15 = lane & 15, lg = lane >> 4;
    const int mh = w >> 1, dh = w & 1;
    const int mbase = mh ? 7 : 0, mcnt = mh ? 6 : 7;
    const int par = lane & 1;
    const int q2  = l15 & ~1;
    const unsigned int psel = par ? 0x03020706u : 0x05040100u;
    const int kk = t >> 4, d4 = t & 15;

    f32x4 acc[7][2];
    #pragma unroll
    for (int m = 0; m < 7; ++m) {
        acc[m][0] = (f32x4){0.f, 0.f, 0.f, 0.f};
        acc[m][1] = (f32x4){0.f, 0.f, 0.f, 0.f};
    }

    // prologue: stage step 0 into buf 0
    {
        const int kb = kb0;
        for (int f = w; f < MT; f += 4)
            gload_lds16(mfrag + ((size_t)(kb * MT + f) * 64 + lane) * 8,
                        &Asd[0][f * 512 + lane * 8]);
        float4 p0 = *(const float4*)&feats[((size_t)kb * BK + kk) * D_ + d0 + d4 * 4];
        float4 p1 = *(const float4*)&feats[((size_t)kb * BK + kk + 16) * D_ + d0 + d4 * 4];
        ushort4 v0 = { f2bf(p0.x), f2bf(p0.y), f2bf(p0.z), f2bf(p0.w) };
        ushort4 v1 = { f2bf(p1.x), f2bf(p1.y), f2bf(p1.z), f2bf(p1.w) };
        *(ushort4*)&Bsd[0][kk * BSTR + d4 * 4] = v0;
        *(ushort4*)&Bsd[0][(kk + 16) * BSTR + d4 * 4] = v1;
    }

    for (int s = 0; s < NSTEPS; ++s) {
        const int cur = s & 1, nxt = cur ^ 1;
        __syncthreads();                           // publishes buf[cur]
        float4 p0, p1;
        const bool pre = (s + 1 < NSTEPS);
        if (pre) {
            const int kb = kb0 + s + 1;
            for (int f = w; f < MT; f += 4)
                gload_lds16(mfrag + ((size_t)(kb * MT + f) * 64 + lane) * 8,
                            &Asd[nxt][f * 512 + lane * 8]);
            p0 = *(const float4*)&feats[((size_t)kb * BK + kk) * D_ + d0 + d4 * 4];
            p1 = *(const float4*)&feats[((size_t)kb * BK + kk + 16) * D_ + d0 + d4 * 4];
        }

        // assemble the wave's two B fragments from buf[cur]
        bf16x8 bf[2];
        #pragma unroll
        for (int sb = 0; sb < 2; ++sb) {
            const int dp = dh * 32 + sb * 16 + q2;
            uint32_t own[4], prt[4], wd[4];
            #pragma unroll
            for (int jj = 0; jj < 4; ++jj) {
                const int k = lg * 8 + 2 * jj + par;
                own[jj] = *(const uint32_t*)&Bsd[cur][k * BSTR + dp];
            }
            #pragma unroll
            for (int jj = 0; jj < 4; ++jj)
                prt[jj] = (uint32_t)__shfl_xor((int)own[jj], 1, 64);
            #pragma unroll
            for (int jj = 0; jj < 4; ++jj)
                wd[jj] = __builtin_amdgcn_perm(prt[jj], own[jj], psel);
            union { uint32_t u[4]; bf16x8 v; } cv;
            cv.u[0] = wd[0]; cv.u[1] = wd[1]; cv.u[2] = wd[2]; cv.u[3] = wd[3];
            bf[sb] = cv.v;
        }

        for (int m = 0; m < mcnt; ++m) {
            bf16x8 af = *(const bf16x8*)&Asd[cur][(mbase + m) * 512 + lane * 8];
            acc[m][0] = __builtin_amdgcn_mfma_f32_16x16x32_bf16(af, bf[0], acc[m][0], 0, 0, 0);
            acc[m][1] = __builtin_amdgcn_mfma_f32_16x16x32_bf16(af, bf[1], acc[m][1], 0, 0, 0);
        }

        if (pre) {
            ushort4 v0 = { f2bf(p0.x), f2bf(p0.y), f2bf(p0.z), f2bf(p0.w) };
            ushort4 v1 = { f2bf(p1.x), f2bf(p1.y), f2bf(p1.z), f2bf(p1.w) };
            *(ushort4*)&Bsd[nxt][kk * BSTR + d4 * 4] = v0;
            *(ushort4*)&Bsd[nxt][(kk + 16) * BSTR + d4 * 4] = v1;
        }
    }

    float* dst = mode ? (outbuf + (size_t)ks * CP * D_) : outbuf;
    for (int m = 0; m < mcnt; ++m) {
        #pragma unroll
        for (int sb = 0; sb < 2; ++sb) {
            const int d = d0 + dh * 32 + sb * 16 + l15;
            #pragma unroll
            for (int r = 0; r < 4; ++r) {
                const int c = (mbase + m) * 16 + lg * 4 + r;
                if (mode) dst[(size_t)c * D_ + d] = acc[m][sb][r];
                else      atomicAdd(&dst[(size_t)c * D_ + d], acc[m][sb][r]);
            }
        }
    }
}

// ---------------------------------------------------------------------------
// Kernel 3: reduce npart partials (npart=1 for the atomic path) + EMA update.
// ---------------------------------------------------------------------------
__global__ __launch_bounds__(256) void epi_kernel(
    const float* __restrict__ proto, const float* __restrict__ part,
    const int* __restrict__ counts, float* __restrict__ out, int npart) {
    const int i4 = blockIdx.x * 256 + threadIdx.x;   // 102400 float4s
    const int c  = i4 >> 9;
    const size_t off = (size_t)(i4 & 511) * 4;
    float4 s = make_float4(0.f, 0.f, 0.f, 0.f);
    for (int p = 0; p < npart; ++p) {
        float4 v = *(const float4*)&part[((size_t)p * CP + c) * D_ + off];
        s.x += v.x; s.y += v.y; s.z += v.z; s.w += v.w;
    }
    float4 pr = *(const float4*)&proto[(size_t)c * D_ + off];
    const int cnt = counts[c];
    float4 o;
    if (cnt > 0) {
        const float inv = 0.001f / (float)cnt;
        const float om  = 1.0f - 0.001f;
        o.x = om * pr.x + s.x * inv;  o.y = om * pr.y + s.y * inv;
        o.z = om * pr.z + s.z * inv;  o.w = om * pr.w + s.w * inv;
    } else o = pr;
    *(float4*)&out[(size_t)c * D_ + off] = o;
}

extern "C" void kernel_launch(void* const* d_in, const int* in_sizes, int n_in,
                              void* d_out, int out_size, void* d_ws, size_t ws_size,
                              hipStream_t stream) {
    const float* feats = (const float*)d_in[0];
    const int*   act   = (const int*)d_in[1];
    const int*   vid   = (const int*)d_in[2];
    const float* proto = (const float*)d_in[3];
    float* out = (float*)d_out;

    const size_t maskB  = (size_t)NKBLK * MT * 64 * 16;        // 13,631,488
    const size_t sumsB  = (size_t)CP * D_ * 4;                 //  1,703,936
    const size_t partB  = (size_t)KSPLIT * CP * D_ * 4;        // 54,525,952
    const size_t needP  = 1024 + partB + maskB;                // ~68.2 MB

    char* ws = (char*)d_ws;
    int* counts = (int*)ws;
    const int mode = (ws_size >= needP) ? 1 : 0;
    float* buf = (float*)(ws + 1024);                          // partials or sums
    unsigned short* mfrag = (unsigned short*)(ws + 1024 + (mode ? partB : sumsB));

    // counts always zeroed; sums zeroed only on atomic path (partials fully overwritten)
    hipMemsetAsync(ws, 0, 1024 + (mode ? 0 : sumsB), stream);
    mask_frag_kernel<<<NKBLK, 256, 0, stream>>>(act, vid, mfrag, counts);
    gemm_kernel<<<32 * KSPLIT, 256, 0, stream>>>(feats, mfrag, buf, mode);
    epi_kernel<<<(C_ * D_ / 4) / 256, 256, 0, stream>>>(proto, buf, counts, out,
                                                        mode ? KSPLIT : 1);
}